// Round 1
// baseline (675.600 us; speedup 1.0000x reference)
//
#include <hip/hip_runtime.h>
#include <math.h>

// InfoNCE loss: B=4096 rows, N=127 negatives, D=256, fp32.  ~541 MB read-once.
// R4: load-path rework vs R3 (646.6 us = 13% of achievable HBM BW):
//  - plain f32x4 loads (nontemporal dropped: 6.3 TB/s ceiling was measured
//    with plain loads; nt is the unverified path and L2 retention is
//    irrelevant for read-once data)
//  - positive/negative select peeled out of the hot loop: group 0 reads
//    positive at it=0, everything else is affine nbase + it*16*D
//  - explicit 2-deep double-buffered pipeline (bufA/bufB), all indices
//    compile-time -> steady 4-8 wave-loads in flight, bounded VGPR
// Structure kept: 1 block/row, 16 groups x 16 lanes, batched group
// reductions off the load path, wave-0 logsumexp, tiny mean kernel.

namespace {
constexpr int B = 4096;
constexpr int N = 127;
constexpr int D = 256;
constexpr int V = N + 1;
constexpr float INV_TEMP = 1.0f / 0.07f;
constexpr float EPS = 1e-12f;

typedef float f32x4 __attribute__((ext_vector_type(4)));

__device__ __forceinline__ float group16_reduce_sum(float v) {
    #pragma unroll
    for (int off = 1; off < 16; off <<= 1) v += __shfl_xor(v, off, 64);
    return v;
}
__device__ __forceinline__ float wave_reduce_sum(float v) {
    #pragma unroll
    for (int off = 32; off > 0; off >>= 1) v += __shfl_xor(v, off, 64);
    return v;
}
__device__ __forceinline__ float wave_reduce_max(float v) {
    #pragma unroll
    for (int off = 32; off > 0; off >>= 1) v = fmaxf(v, __shfl_xor(v, off, 64));
    return v;
}

// 4 x 16B loads: lane's slice of one 256-float vector (sub pre-applied in p).
__device__ __forceinline__ void load4(f32x4 (&buf)[4], const float* p) {
    #pragma unroll
    for (int i = 0; i < 4; ++i)
        buf[i] = *reinterpret_cast<const f32x4*>(p + i * 64);
}

__device__ __forceinline__ void acc4(float& d, float& s,
                                     const f32x4 (&aa)[4], const f32x4 (&x)[4]) {
    float dd = 0.f, ss = 0.f;
    #pragma unroll
    for (int i = 0; i < 4; ++i) {
        dd += aa[i].x * x[i].x + aa[i].y * x[i].y + aa[i].z * x[i].z + aa[i].w * x[i].w;
        ss += x[i].x * x[i].x + x[i].y * x[i].y + x[i].z * x[i].z + x[i].w * x[i].w;
    }
    d = dd; s = ss;
}
} // namespace

__global__ __launch_bounds__(256) void infonce_rows(
    const float* __restrict__ anchor,
    const float* __restrict__ positive,
    const float* __restrict__ negatives,
    float* __restrict__ row_loss)
{
    const int b   = blockIdx.x;
    const int tid = threadIdx.x;
    const int sub = tid & 15;   // lane within 16-group
    const int g   = tid >> 4;   // 16-group id, 0..15

    __shared__ float scores[V];

    // --- anchor fragment: lane holds elements {i*64 + sub*4 .. +3} ---
    const float* arow = anchor + (size_t)b * D + sub * 4;
    f32x4 aa[4];
    load4(aa, arow);
    float asq = 0.f;
    #pragma unroll
    for (int i = 0; i < 4; ++i)
        asq += aa[i].x * aa[i].x + aa[i].y * aa[i].y + aa[i].z * aa[i].z + aa[i].w * aa[i].w;
    asq = group16_reduce_sum(asq);
    const float ainv = 1.0f / fmaxf(sqrtf(asq), EPS);
    #pragma unroll
    for (int i = 0; i < 4; ++i) aa[i] *= ainv;

    // --- affine streaming base: vector v = g + 16*it lives (for v>=1) at
    // negatives[(b*N + v - 1)*D]; nbase folds in (g-1), step is 16*D floats.
    // For g==0 nbase is only dereferenced from it>=1 (offset >= 15*D > 0). ---
    const float* nbase = negatives
        + ((ptrdiff_t)b * N + (ptrdiff_t)g - 1) * D + sub * 4;
    const float* p0 = (g == 0) ? (positive + (size_t)b * D + sub * 4) : nbase;

    float dot[8], sq[8];
    f32x4 bufA[4], bufB[4];
    load4(bufA, p0);                                   // it = 0
    #pragma unroll
    for (int itp = 0; itp < 4; ++itp) {
        const int it0 = 2 * itp, it1 = it0 + 1;
        load4(bufB, nbase + (size_t)it1 * 16 * D);     // prefetch odd it
        acc4(dot[it0], sq[it0], aa, bufA);             // consume even it
        if (it1 + 1 < 8)
            load4(bufA, nbase + (size_t)(it1 + 1) * 16 * D);  // prefetch even it
        acc4(dot[it1], sq[it1], aa, bufB);             // consume odd it
    }

    // --- batched group reductions (off the memory path) ---
    #pragma unroll
    for (int it = 0; it < 8; ++it) {
        const float d = group16_reduce_sum(dot[it]);
        const float s = group16_reduce_sum(sq[it]);
        if (sub == 0)
            scores[g + 16 * it] = d / fmaxf(sqrtf(s), EPS);
    }
    __syncthreads();

    // --- logsumexp over 128 logits (first wave) ---
    if (tid < 64) {
        const float s0 = scores[tid]      * INV_TEMP;
        const float s1 = scores[tid + 64] * INV_TEMP;
        float m = wave_reduce_max(fmaxf(s0, s1));
        float e = expf(s0 - m) + expf(s1 - m);
        e = wave_reduce_sum(e);
        if (tid == 0)
            row_loss[b] = m + logf(e) - scores[0] * INV_TEMP;
    }
}

__global__ __launch_bounds__(256) void reduce_mean(
    const float* __restrict__ row_loss, float* __restrict__ out)
{
    __shared__ float wsum[4];
    const int tid  = threadIdx.x;
    const int wave = tid >> 6;
    const int lane = tid & 63;

    float s = 0.0f;
    for (int i = tid; i < B; i += 256) s += row_loss[i];
    s = wave_reduce_sum(s);
    if (lane == 0) wsum[wave] = s;
    __syncthreads();
    if (tid == 0)
        out[0] = (wsum[0] + wsum[1] + wsum[2] + wsum[3]) * (1.0f / (float)B);
}

extern "C" void kernel_launch(void* const* d_in, const int* in_sizes, int n_in,
                              void* d_out, int out_size, void* d_ws, size_t ws_size,
                              hipStream_t stream) {
    const float* anchor    = (const float*)d_in[0];
    const float* positive  = (const float*)d_in[1];
    const float* negatives = (const float*)d_in[2];
    float* out      = (float*)d_out;
    float* row_loss = (float*)d_ws;   // B floats = 16 KB scratch

    infonce_rows<<<B, 256, 0, stream>>>(anchor, positive, negatives, row_loss);
    reduce_mean<<<1, 256, 0, stream>>>(row_loss, out);
}